// Round 10
// baseline (212.550 us; speedup 1.0000x reference)
//
#include <hip/hip_runtime.h>

// NetVLAD fused kernel for MI355X (gfx950).
// Shapes: x[N=64][C=128][S=4096] fp32, conv_w[K=64][C=128], centroids[K=64][C=128].
// out[N][K*C] fp32.
//
// R16 = R14 skeleton (best: 206.66us) with the convert phase DELETED via
// global_load_lds f32 staging. Evidence: occupancy x3, barrier count (R15),
// LDS issue count (-1us), VALU count (-3us) all refuted as limiters; the
// untested chunk-phase component is the pre-barrier serial segment
// (vmcnt-wait -> 16 cvt -> 8 ds_write). Replace register staging with
// 32 fire-and-forget global_load_lds (width 4 = one 256B f32 row/wave-op:
// wave-uniform LDS base + lane*4; per-lane global src). f32->bf16 moves to
// fragment-read time (cvt_pk, overlaps MFMA). Pre-barrier segment becomes
// a bare s_waitcnt vmcnt(0), covered by the previous chunk's compute.
//  - BA barrier: vmcnt(0)+lgkmcnt(0) (staging(ch) landed); BB: lgkm-only
//    (staging(ch+1) stays in flight across it)
//  - v[8] eliminated: -32 VGPR, spill cliff structurally gone
//  - LDS: xf32[2][128][68dw] 69.6KB + a_ks 9.2KB = 78.8KB -> 2 blocks/CU
//  - P1 gather: 8 f32 dword reads/frag (rotation (i+2l4)&7 -> all 32 banks,
//    2-way free) + 4 cvt_pk; P3 bfx: 2 float4 reads + 4 cvt_pk (8-way bank,
//    same class R14's constant 786k counter already paid)
// Unchanged: Pp=8, CH=8, TS=64, dbuf, cvt_pk everywhere, partial-sum
// stores, __launch_bounds__(256,2).
// Certificates: VGPR ~85-100, WRITE 16.4MB, FETCH ~66MB.

#define Nn 64
#define Cc 128
#define Ss 4096
#define Kk 64
#define TS 64
#define CH 8
#define SB (TS*CH)
#define Pp 8    // s-slabs == partial buffers

typedef __attribute__((ext_vector_type(8))) short bf16x8;
typedef __attribute__((ext_vector_type(4))) float f32x4;

// HW packed f32->bf16 (RNE): dst.lo = bf16(a), dst.hi = bf16(b). 1 VALU op.
__device__ __forceinline__ unsigned cvt2(float a, float b) {
  unsigned r;
  asm("v_cvt_pk_bf16_f32 %0, %1, %2" : "=v"(r) : "v"(a), "v"(b));
  return r;
}

// Async global->LDS, 4B/lane: LDS dest = wave-uniform base + lane*4,
// global src = per-lane address. Counted by vmcnt.
__device__ __forceinline__ void gload_lds4(const float* g, float* l) {
  __builtin_amdgcn_global_load_lds(
      (const __attribute__((address_space(1))) void*)g,
      (__attribute__((address_space(3))) void*)l, 4, 0, 0);
}

// BB barrier: waits LDS ops only (lgkmcnt), NOT in-flight global_load_lds
// (vmcnt) -- keeps next-chunk staging in flight across the barrier.
__device__ __forceinline__ void bar_lds() {
  asm volatile("s_waitcnt lgkmcnt(0)\n\ts_barrier" ::: "memory");
}
// BA barrier: drains this chunk's staging (vmcnt) + LDS ops, then syncs.
__device__ __forceinline__ void bar_full() {
  asm volatile("s_waitcnt vmcnt(0) lgkmcnt(0)\n\ts_barrier" ::: "memory");
}

// LDS strides. xf32 rows: 64 f32 + 4 pad = 68 dwords = 272B (16B-aligned;
// 68 mod 32 = 4 -> row-to-row bank shift of 4 for the rotated gather).
#define XF_STR 68     // xf32[2][128][68] dwords
#define AKS_STR 72    // a_ks[64][72] halves (144B rows)

__launch_bounds__(256, 2)
__global__ void netvlad_main(const float* __restrict__ x,
                             const float* __restrict__ w,
                             float* __restrict__ vlad,   // [P][N][K][C] partials, or [N][K][C] zeroed (atomic)
                             float* __restrict__ asum,   // [P][N][K] partials,    or [N][K] zeroed (atomic)
                             int use_atomic)
{
  __shared__ __align__(16) float xf32[2][Cc][XF_STR];            // x[c][s] f32, double-buffered
  __shared__ __align__(16) unsigned short a_ks[Kk][AKS_STR];     // a[k][s] bf16

  const int t    = threadIdx.x;
  const int wv   = t >> 6;          // wave 0..3
  const int lane = t & 63;
  const int l15  = t & 15;
  const int l4   = (t >> 4) & 3;    // lane quad within wave
  const int n    = blockIdx.y;
  const int sb   = blockIdx.x;      // s-slab 0..7
  const size_t xbase = (size_t)n * Cc * Ss;

  // per-lane global base for staging: lane i covers s-offset i of each row
  const float* gx = x + xbase + (size_t)sb * SB + lane;

  // ---- preload W fragments into registers (A-operand of P1) ----
  // A[m=k][kd=c]: lane holds A[16*mt + l15][32*q + 8*l4 + j], j=0..7
  bf16x8 wfrag[4][4];
#pragma unroll
  for (int mt = 0; mt < 4; ++mt) {
#pragma unroll
    for (int q = 0; q < 4; ++q) {
      const float* wp = w + (16*mt + l15) * Cc + 32*q + 8*l4;
      float4 a = *(const float4*)wp;
      float4 b = *(const float4*)(wp + 4);
      int4 pk = make_int4((int)cvt2(a.x, a.y), (int)cvt2(a.z, a.w),
                          (int)cvt2(b.x, b.y), (int)cvt2(b.z, b.w));
      wfrag[mt][q] = *(bf16x8*)&pk;
    }
  }

  // persistent accumulators
  f32x4 acc3[4][2];                 // [mt(k-tile)][tc(c-tile within wave's 32c)]
#pragma unroll
  for (int mt = 0; mt < 4; ++mt)
#pragma unroll
    for (int tc = 0; tc < 2; ++tc) acc3[mt][tc] = (f32x4){0.f,0.f,0.f,0.f};
  float asum_reg[4][4];             // [mt][r]
#pragma unroll
  for (int mt = 0; mt < 4; ++mt)
#pragma unroll
    for (int r = 0; r < 4; ++r) asum_reg[mt][r] = 0.f;

  // ---- async staging: wave wv owns rows c = 32*wv + i, one row per op ----
  auto stage = [&](int buf, int ch) {
#pragma unroll
    for (int i = 0; i < 32; ++i) {
      const int c = 32*wv + i;
      gload_lds4(gx + (size_t)c * Ss + ch * TS, &xf32[buf][c][0]);
    }
  };

  // prologue: fire chunk 0's staging
  stage(0, 0);

  for (int ch = 0; ch < CH; ++ch) {
    const int buf = ch & 1;

    bar_full();  // BA: staging(ch) landed (vmcnt), prior chunk's readers of
                 // xf32[buf] and a_ks drained (lgkm+barrier).

    // ---- fire next chunk's staging; stays in flight across BB ----
    if (ch + 1 < CH) stage(buf ^ 1, ch + 1);

    // ---- build P1 B-frags from xf32[buf] columns (f32 reads + cvt_pk) ----
    // bfr[q][j'] = x[c = 32q + 8*l4 + j'][s = 16*wv + l15]
    // rotation (i+2*l4)&7: bank = (4i + 8l4 + l15)&31 -> all 32 banks, 2-way
    const int scol = 16*wv + l15;
    bf16x8 bfr[4];
#pragma unroll
    for (int j = 0; j < 4; ++j) {
      const int c8 = 32*j + 8*l4;
      float h[8];
#pragma unroll
      for (int i = 0; i < 8; ++i) {
        const int i2 = (i + 2*l4) & 7;
        h[i2] = xf32[buf][c8 + i2][scol];
      }
      int4 pk;
      pk.x = (int)cvt2(h[0], h[1]);
      pk.y = (int)cvt2(h[2], h[3]);
      pk.z = (int)cvt2(h[4], h[5]);
      pk.w = (int)cvt2(h[6], h[7]);
      bfr[j] = *(bf16x8*)&pk;
    }

    // ---- P1: logits tile. wave wv owns s-tile [16*wv,16*wv+16), all 64 k ----
    f32x4 acc1[4];
#pragma unroll
    for (int mt = 0; mt < 4; ++mt) acc1[mt] = (f32x4){0.f,0.f,0.f,0.f};
#pragma unroll
    for (int q = 0; q < 4; ++q) {
#pragma unroll
      for (int mt = 0; mt < 4; ++mt)
        acc1[mt] = __builtin_amdgcn_mfma_f32_16x16x32_bf16(wfrag[mt][q], bfr[q], acc1[mt], 0, 0, 0);
    }

    // ---- softmax over k, fully in-wave ----
    // C/D layout: col s = 16*wv + l15, row k = 16*mt + 4*l4 + r
    float e[4][4];
    float cs = 0.f;
#pragma unroll
    for (int mt = 0; mt < 4; ++mt)
#pragma unroll
      for (int r = 0; r < 4; ++r) {
        float ev = __expf(acc1[mt][r]);
        e[mt][r] = ev;
        cs += ev;
      }
    cs += __shfl_xor(cs, 16, 64);
    cs += __shfl_xor(cs, 32, 64);
    const float inv = 1.0f / cs;
#pragma unroll
    for (int mt = 0; mt < 4; ++mt)
#pragma unroll
      for (int r = 0; r < 4; ++r) {
        float an = e[mt][r] * inv;
        asum_reg[mt][r] += an;
        a_ks[16*mt + 4*l4 + r][16*wv + l15] = (unsigned short)cvt2(an, an);
      }
    bar_lds();   // BB: a_ks ready (lgkm only -- staging stays in flight)

    // ---- P3: vlad += A @ X^T. wave wv owns c in [32*wv, 32*wv+32) ----
#pragma unroll
    for (int q2 = 0; q2 < 2; ++q2) {
      bf16x8 afr[4];
#pragma unroll
      for (int mt = 0; mt < 4; ++mt)
        afr[mt] = *(bf16x8*)&a_ks[16*mt + l15][32*q2 + 8*l4];
#pragma unroll
      for (int tc = 0; tc < 2; ++tc) {
        const float* xr = &xf32[buf][32*wv + 16*tc + l15][32*q2 + 8*l4];
        float4 xa = *(const float4*)xr;
        float4 xb = *(const float4*)(xr + 4);
        int4 pk = make_int4((int)cvt2(xa.x, xa.y), (int)cvt2(xa.z, xa.w),
                            (int)cvt2(xb.x, xb.y), (int)cvt2(xb.z, xb.w));
        bf16x8 bfx = *(bf16x8*)&pk;
#pragma unroll
        for (int mt = 0; mt < 4; ++mt)
          acc3[mt][tc] = __builtin_amdgcn_mfma_f32_16x16x32_bf16(afr[mt], bfx, acc3[mt][tc], 0, 0, 0);
      }
    }
    // no end-of-chunk barrier: staging(ch+1) writes xf32[buf^1] (readers of
    // it drained at BA(ch)); a_ks rewrite (ch+1) fenced by BA(ch+1).
  }

  // ---- block epilogue: asum cross-wave reduction via LDS, then stores ----
  bar_lds();                    // all P3 a_ks reads drained before reuse
  float* asml = (float*)a_ks;
#pragma unroll
  for (int mt = 0; mt < 4; ++mt) {
#pragma unroll
    for (int r = 0; r < 4; ++r) {
      float vv = asum_reg[mt][r];
      vv += __shfl_xor(vv, 1, 64);
      vv += __shfl_xor(vv, 2, 64);
      vv += __shfl_xor(vv, 4, 64);
      vv += __shfl_xor(vv, 8, 64);
      if (l15 == 0) asml[wv * Kk + 16*mt + 4*l4 + r] = vv;
    }
  }
  bar_lds();
  if (t < Kk) {
    float s = asml[t] + asml[Kk + t] + asml[2*Kk + t] + asml[3*Kk + t];
    if (use_atomic) atomicAdd(&asum[n * Kk + t], s);
    else            asum[((size_t)sb * Nn + n) * Kk + t] = s;
  }

  if (use_atomic) {
#pragma unroll
    for (int mt = 0; mt < 4; ++mt)
#pragma unroll
      for (int tc = 0; tc < 2; ++tc)
#pragma unroll
        for (int r = 0; r < 4; ++r) {
          const int k = 16*mt + 4*l4 + r;
          const int c = 32*wv + 16*tc + l15;
          atomicAdd(&vlad[((size_t)n * Kk + k) * Cc + c], acc3[mt][tc][r]);
        }
  } else {
    float* vp = vlad + ((size_t)sb * Nn + n) * (Kk * Cc);
#pragma unroll
    for (int mt = 0; mt < 4; ++mt)
#pragma unroll
      for (int tc = 0; tc < 2; ++tc)
#pragma unroll
        for (int r = 0; r < 4; ++r) {
          const int k = 16*mt + 4*l4 + r;
          const int c = 32*wv + 16*tc + l15;
          vp[k * Cc + c] = acc3[mt][tc][r];   // streaming, coalesced per 16 lanes
        }
  }
}

__global__ void netvlad_epilogue(const float* __restrict__ vlad,  // [P][N][K][C] or [N][K][C]
                                 const float* __restrict__ asum,  // [P][N][K]    or [N][K]
                                 const float* __restrict__ cent,
                                 float* __restrict__ out,
                                 int nparts)
{
  const int n  = blockIdx.x;
  const int k  = 16*blockIdx.y + (threadIdx.x >> 4);
  const int cq = threadIdx.x & 15;   // 16 threads per k, 8 c each

  float ak = 0.f;
  float4 x0 = make_float4(0.f, 0.f, 0.f, 0.f);
  float4 x1 = make_float4(0.f, 0.f, 0.f, 0.f);
  for (int p = 0; p < nparts; ++p) {
    ak += asum[((size_t)p * Nn + n) * Kk + k];
    const float* vp = vlad + (((size_t)p * Nn + n) * Kk + k) * Cc + 8*cq;
    float4 a0 = *(const float4*)vp;
    float4 a1 = *(const float4*)(vp + 4);
    x0.x += a0.x; x0.y += a0.y; x0.z += a0.z; x0.w += a0.w;
    x1.x += a1.x; x1.y += a1.y; x1.z += a1.z; x1.w += a1.w;
  }

  const size_t cbse = (size_t)k * Cc + 8*cq;
  float4 c0 = *(const float4*)(cent + cbse);
  float4 c1 = *(const float4*)(cent + cbse + 4);
  float4 r0, r1;
  r0.x = x0.x - ak*c0.x; r0.y = x0.y - ak*c0.y; r0.z = x0.z - ak*c0.z; r0.w = x0.w - ak*c0.w;
  r1.x = x1.x - ak*c1.x; r1.y = x1.y - ak*c1.y; r1.z = x1.z - ak*c1.z; r1.w = x1.w - ak*c1.w;
  float ss = r0.x*r0.x + r0.y*r0.y + r0.z*r0.z + r0.w*r0.w
           + r1.x*r1.x + r1.y*r1.y + r1.z*r1.z + r1.w*r1.w;
  ss += __shfl_xor(ss, 1, 64);
  ss += __shfl_xor(ss, 2, 64);
  ss += __shfl_xor(ss, 4, 64);
  ss += __shfl_xor(ss, 8, 64);
  // intra-norm; global norm is exactly sqrt(K)=8 since rows are unit norm
  const float rn = rsqrtf(ss) * 0.125f;
  r0.x *= rn; r0.y *= rn; r0.z *= rn; r0.w *= rn;
  r1.x *= rn; r1.y *= rn; r1.z *= rn; r1.w *= rn;
  float* op = out + (size_t)n * (Kk * Cc) + (size_t)k * Cc + 8*cq;
  *(float4*)op = r0;
  *(float4*)(op + 4) = r1;
}

extern "C" void kernel_launch(void* const* d_in, const int* in_sizes, int n_in,
                              void* d_out, int out_size, void* d_ws, size_t ws_size,
                              hipStream_t stream)
{
  const float* x    = (const float*)d_in[0];
  const float* w    = (const float*)d_in[1];
  const float* cent = (const float*)d_in[2];
  float* out = (float*)d_out;

  const size_t vlad_elems_p = (size_t)Pp * Nn * Kk * Cc;
  const size_t asum_elems_p = (size_t)Pp * Nn * Kk;
  const size_t need = (vlad_elems_p + asum_elems_p) * sizeof(float);

  if (ws_size >= need) {
    // partial-sum path: no atomics, no memset
    float* vlad_part = (float*)d_ws;
    float* asum_part = vlad_part + vlad_elems_p;
    netvlad_main<<<dim3(Pp, Nn), 256, 0, stream>>>(x, w, vlad_part, asum_part, 0);
    netvlad_epilogue<<<dim3(Nn, 4), 256, 0, stream>>>(vlad_part, asum_part, cent, out, Pp);
  } else {
    // atomic fallback
    float* vlad = (float*)d_ws;
    float* asum = vlad + (size_t)Nn * Kk * Cc;
    const size_t zbytes = ((size_t)Nn * Kk * Cc + (size_t)Nn * Kk) * sizeof(float);
    hipMemsetAsync(d_ws, 0, zbytes, stream);
    netvlad_main<<<dim3(Pp, Nn), 256, 0, stream>>>(x, w, vlad, asum, 1);
    netvlad_epilogue<<<dim3(Nn, 4), 256, 0, stream>>>(vlad, asum, cent, out, 1);
  }
}